// Round 2
// baseline (5218.700 us; speedup 1.0000x reference)
//
#include <hip/hip_runtime.h>
#include <hip/hip_bf16.h>

#define NN 100000
#define NT 2000000
#define HD 48

__device__ __forceinline__ float b2f(__hip_bfloat16 x) { return __bfloat162float(x); }

// Load a "float tensor" element whose storage is bf16 (flag=1) or f32 (flag=0).
__device__ __forceinline__ float ldf(const void* p, long long i, int isbf16) {
    if (isbf16) return b2f(((const __hip_bfloat16*)p)[i]);
    return ((const float*)p)[i];
}

// ---------------------------------------------------------------------------
// Kernel P: probe dtypes from raw bits.
// flags[0] = float tensors stored as bf16?   flags[1] = indices stored as int64?
// ---------------------------------------------------------------------------
__global__ void probe_kernel(const unsigned int* __restrict__ hw,
                             const unsigned int* __restrict__ iw,
                             int* __restrict__ flags) {
    __shared__ int cnt_bf, cnt_idx;
    if (threadIdx.x == 0) { cnt_bf = 0; cnt_idx = 0; }
    __syncthreads();
    unsigned int w = hw[threadIdx.x];
    unsigned int e = (w >> 7) & 0xff;            // exponent field of low-half bf16
    if (e >= 90 && e <= 144) atomicAdd(&cnt_bf, 1);
    if (iw[2 * threadIdx.x + 1] == 0) atomicAdd(&cnt_idx, 1);
    __syncthreads();
    if (threadIdx.x == 0) {
        flags[0] = (cnt_bf >= 192) ? 1 : 0;      // bf16 ~256 hits; f32 mantissa ~55
        flags[1] = (cnt_idx >= 255) ? 1 : 0;     // int64 high words all zero
    }
}

// ---------------------------------------------------------------------------
// Kernel 0: fold weights. wu1f[o][h] = Wu[o][h]; bf[o][h] = sum_k Wu[o][48+k]*W3[k][h]
// ---------------------------------------------------------------------------
__global__ void prep_kernel(const void* __restrict__ W3,
                            const void* __restrict__ Wu,
                            const int* __restrict__ flags,
                            float* __restrict__ wu1f, float* __restrict__ bf) {
    int i = blockIdx.x * blockDim.x + threadIdx.x;
    if (i >= HD * HD) return;
    int fb = flags[0];
    int o = i / HD, hh = i % HD;
    wu1f[i] = ldf(Wu, o * 2 * HD + hh, fb);
    float s = 0.f;
    #pragma unroll 8
    for (int k = 0; k < HD; ++k)
        s += ldf(Wu, o * 2 * HD + HD + k, fb) * ldf(W3, k * HD + hh, fb);
    bf[i] = s;
}

// ---------------------------------------------------------------------------
// Kernel 1: per-node u[n] = Wu1*h[n], v[n] = M*h[n].  192 thr = 4 nodes x 48 out.
// Weight rows in LDS with stride 49 (odd stride -> worst 2-way aliasing, free).
// ---------------------------------------------------------------------------
__global__ __launch_bounds__(192) void node_kernel(
        const void* __restrict__ h, const int* __restrict__ flags,
        const float* __restrict__ wu1f, const float* __restrict__ bf,
        float* __restrict__ u, float* __restrict__ v) {
    __shared__ float Wu1s[HD * 49];
    __shared__ float Bs[HD * 49];
    __shared__ float hs[192];
    int tid = threadIdx.x;
    int fb = flags[0];
    for (int i = tid; i < HD * HD; i += 192) {
        int o = i / HD, hh = i % HD;
        Wu1s[o * 49 + hh] = wu1f[i];
        Bs[o * 49 + hh]   = bf[i];
    }
    int base = blockIdx.x * 4;                    // NN % 4 == 0
    hs[tid] = ldf(h, (long long)base * HD + tid, fb);
    __syncthreads();

    int o  = tid % HD;
    int ln = tid / HD;
    const float* hrow = hs + ln * HD;
    const float* wr = Wu1s + o * 49;
    const float* br = Bs + o * 49;
    float su = 0.f, sv = 0.f;
    #pragma unroll
    for (int k = 0; k < HD; ++k) {
        float hv = hrow[k];
        su += wr[k] * hv;
        sv += br[k] * hv;
    }
    int n = base + ln;
    u[(size_t)n * HD + o] = su;
    v[(size_t)n * HD + o] = sv;
}

// ---------------------------------------------------------------------------
// Kernel 2: per-triple. pre = u[c]+v[n1]+v[n2]; delta = leaky(pre)*w; atomic scatter.
// ---------------------------------------------------------------------------
__global__ __launch_bounds__(256) void triple_kernel(
        const void* __restrict__ idxp,
        const void* __restrict__ d1p, const void* __restrict__ d2p,
        const int* __restrict__ flags,
        const float* __restrict__ u, const float* __restrict__ v,
        float* __restrict__ agg, float* __restrict__ ncf) {
    int t = blockIdx.x * 256 + threadIdx.x;
    if (t >= NT) return;
    int fb = flags[0], fi = flags[1];
    int c, n1, n2;
    if (fi) {
        const long long* q = (const long long*)idxp;
        c  = (int)q[3 * (long long)t + 0];
        n1 = (int)q[3 * (long long)t + 1];
        n2 = (int)q[3 * (long long)t + 2];
    } else {
        const int* q = (const int*)idxp;
        c = q[3 * t + 0]; n1 = q[3 * t + 1]; n2 = q[3 * t + 2];
    }
    float d1 = ldf(d1p, t, fb);
    float d2 = ldf(d2p, t, fb);
    float mx = fmaxf(d1, d2);
    float w = 1.0f + 0.3f * (fabsf(d1 - d2) / (mx + 1e-8f));

    const float4* uc = (const float4*)(u + (size_t)c  * HD);
    const float4* v1 = (const float4*)(v + (size_t)n1 * HD);
    const float4* v2 = (const float4*)(v + (size_t)n2 * HD);
    float* ac = agg + (size_t)c * HD;

    #pragma unroll
    for (int j = 0; j < HD / 4; ++j) {
        float4 a = uc[j];
        float4 b = v1[j];
        float4 cc = v2[j];
        float p0 = a.x + b.x + cc.x;
        float p1 = a.y + b.y + cc.y;
        float p2 = a.z + b.z + cc.z;
        float p3 = a.w + b.w + cc.w;
        p0 = (p0 > 0.f ? p0 : 0.01f * p0) * w;
        p1 = (p1 > 0.f ? p1 : 0.01f * p1) * w;
        p2 = (p2 > 0.f ? p2 : 0.01f * p2) * w;
        p3 = (p3 > 0.f ? p3 : 0.01f * p3) * w;
        atomicAdd(ac + 4 * j + 0, p0);
        atomicAdd(ac + 4 * j + 1, p1);
        atomicAdd(ac + 4 * j + 2, p2);
        atomicAdd(ac + 4 * j + 3, p3);
    }
    atomicAdd(ncf + c, 1.0f);
}

// ---------------------------------------------------------------------------
// Kernel 3: out = LayerNorm(h + agg*rsqrt(max(nc,1))). One wave per node.
// ---------------------------------------------------------------------------
__global__ __launch_bounds__(256) void out_kernel(
        const void* __restrict__ h, const int* __restrict__ flags,
        const float* __restrict__ agg, const float* __restrict__ ncf,
        const void* __restrict__ gamma, const void* __restrict__ beta,
        void* __restrict__ out) {
    int wv = threadIdx.x >> 6;
    int lane = threadIdx.x & 63;
    int n = blockIdx.x * 4 + wv;                  // NN % 4 == 0
    int fb = flags[0];
    float rnc = rsqrtf(fmaxf(ncf[n], 1.0f));
    float x = 0.f;
    if (lane < HD)
        x = ldf(h, (long long)n * HD + lane, fb) + agg[(size_t)n * HD + lane] * rnc;
    float s = x, sq = x * x;
    #pragma unroll
    for (int off = 32; off; off >>= 1) {
        s  += __shfl_xor(s, off, 64);
        sq += __shfl_xor(sq, off, 64);
    }
    float mu  = s * (1.0f / HD);
    float var = sq * (1.0f / HD) - mu * mu;
    float rstd = rsqrtf(var + 1e-5f);
    if (lane < HD) {
        float g  = ldf(gamma, lane, fb);
        float bb = ldf(beta, lane, fb);
        float r = (x - mu) * rstd * g + bb;
        if (fb) ((__hip_bfloat16*)out)[(size_t)n * HD + lane] = __float2bfloat16(r);
        else    ((float*)out)[(size_t)n * HD + lane] = r;
    }
}

extern "C" void kernel_launch(void* const* d_in, const int* in_sizes, int n_in,
                              void* d_out, int out_size, void* d_ws, size_t ws_size,
                              hipStream_t stream) {
    const void* h     = d_in[0];
    const void* idx   = d_in[1];
    const void* d1    = d_in[2];
    const void* d2    = d_in[3];
    const void* W3    = d_in[4];
    const void* Wu    = d_in[5];
    const void* gamma = d_in[6];
    const void* beta  = d_in[7];

    float* ws   = (float*)d_ws;
    int*  flags = (int*)ws;                         // 16 B
    float* wu1f = ws + 16;                          // 2304
    float* bf   = wu1f + HD * HD;                   // 2304
    float* u    = bf + HD * HD;                     // NN*48
    float* v    = u + (size_t)NN * HD;              // NN*48
    float* agg  = v + (size_t)NN * HD;              // NN*48
    float* ncf  = agg + (size_t)NN * HD;            // NN

    // zero accumulators (ws is re-poisoned 0xAA before every call)
    hipMemsetAsync(agg, 0, ((size_t)NN * HD + NN) * sizeof(float), stream);

    probe_kernel<<<1, 256, 0, stream>>>((const unsigned int*)h,
                                        (const unsigned int*)idx, flags);
    prep_kernel<<<(HD * HD + 255) / 256, 256, 0, stream>>>(W3, Wu, flags, wu1f, bf);
    node_kernel<<<NN / 4, 192, 0, stream>>>(h, flags, wu1f, bf, u, v);
    triple_kernel<<<(NT + 255) / 256, 256, 0, stream>>>(idx, d1, d2, flags, u, v, agg, ncf);
    out_kernel<<<NN / 4, 256, 0, stream>>>(h, flags, agg, ncf, gamma, beta, d_out);
}

// Round 3
// 879.797 us; speedup vs baseline: 5.9317x; 5.9317x over previous
//
#include <hip/hip_runtime.h>
#include <hip/hip_bf16.h>

#define NN 100000
#define NT 2000000
#define HD 48

__device__ __forceinline__ float b2f(__hip_bfloat16 x) { return __bfloat162float(x); }

// Load a "float tensor" element whose storage is bf16 (flag=1) or f32 (flag=0).
__device__ __forceinline__ float ldf(const void* p, long long i, int isbf16) {
    if (isbf16) return b2f(((const __hip_bfloat16*)p)[i]);
    return ((const float*)p)[i];
}

// ---------------------------------------------------------------------------
// Kernel P: probe dtypes from raw bits.
// flags[0] = float tensors stored as bf16?   flags[1] = indices stored as int64?
// ---------------------------------------------------------------------------
__global__ void probe_kernel(const unsigned int* __restrict__ hw,
                             const unsigned int* __restrict__ iw,
                             int* __restrict__ flags) {
    __shared__ int cnt_bf, cnt_idx;
    if (threadIdx.x == 0) { cnt_bf = 0; cnt_idx = 0; }
    __syncthreads();
    unsigned int w = hw[threadIdx.x];
    unsigned int e = (w >> 7) & 0xff;            // exponent field of low-half bf16
    if (e >= 90 && e <= 144) atomicAdd(&cnt_bf, 1);
    if (iw[2 * threadIdx.x + 1] == 0) atomicAdd(&cnt_idx, 1);
    __syncthreads();
    if (threadIdx.x == 0) {
        flags[0] = (cnt_bf >= 192) ? 1 : 0;      // bf16 ~256 hits; f32 mantissa ~55
        flags[1] = (cnt_idx >= 255) ? 1 : 0;     // int64 high words all zero
    }
}

// ---------------------------------------------------------------------------
// Kernel 0: fold weights. wu1f[o][h] = Wu[o][h]; bf[o][h] = sum_k Wu[o][48+k]*W3[k][h]
// ---------------------------------------------------------------------------
__global__ void prep_kernel(const void* __restrict__ W3,
                            const void* __restrict__ Wu,
                            const int* __restrict__ flags,
                            float* __restrict__ wu1f, float* __restrict__ bf) {
    int i = blockIdx.x * blockDim.x + threadIdx.x;
    if (i >= HD * HD) return;
    int fb = flags[0];
    int o = i / HD, hh = i % HD;
    wu1f[i] = ldf(Wu, o * 2 * HD + hh, fb);
    float s = 0.f;
    #pragma unroll 8
    for (int k = 0; k < HD; ++k)
        s += ldf(Wu, o * 2 * HD + HD + k, fb) * ldf(W3, k * HD + hh, fb);
    bf[i] = s;
}

// ---------------------------------------------------------------------------
// Kernel 1: per-node v[n] = M*h[n] only (u is folded into accum on the fly).
// 192 thr = 4 nodes x 48 outputs. LDS stride 49 -> worst 2-way aliasing (free).
// ---------------------------------------------------------------------------
__global__ __launch_bounds__(192) void node_kernel(
        const void* __restrict__ h, const int* __restrict__ flags,
        const float* __restrict__ bf, float* __restrict__ v) {
    __shared__ float Bs[HD * 49];
    __shared__ float hs[192];
    int tid = threadIdx.x;
    int fb = flags[0];
    for (int i = tid; i < HD * HD; i += 192)
        Bs[(i / HD) * 49 + (i % HD)] = bf[i];
    int base = blockIdx.x * 4;                    // NN % 4 == 0
    hs[tid] = ldf(h, (long long)base * HD + tid, fb);
    __syncthreads();

    int o  = tid % HD;
    int ln = tid / HD;
    const float* hrow = hs + ln * HD;
    const float* br = Bs + o * 49;
    float sv = 0.f;
    #pragma unroll
    for (int k = 0; k < HD; ++k) sv += br[k] * hrow[k];
    v[(size_t)(base + ln) * HD + o] = sv;
}

// ---------------------------------------------------------------------------
// Kernel 2: histogram of centers.
// ---------------------------------------------------------------------------
__global__ __launch_bounds__(256) void hist_kernel(const void* __restrict__ idxp,
                                                   const int* __restrict__ flags,
                                                   int* __restrict__ cnt) {
    int t = blockIdx.x * 256 + threadIdx.x;
    if (t >= NT) return;
    int c = flags[1] ? (int)((const long long*)idxp)[3LL * t]
                     : ((const int*)idxp)[3 * t];
    atomicAdd(&cnt[c], 1);
}

// ---------------------------------------------------------------------------
// Kernel 3: single-block exclusive scan of cnt[NN] -> off[NN].
// ---------------------------------------------------------------------------
__global__ __launch_bounds__(1024) void scan_kernel(const int* __restrict__ cnt,
                                                    int* __restrict__ off) {
    __shared__ int wsums[16];
    int tid = threadIdx.x;
    int lane = tid & 63, wv = tid >> 6;
    int carry = 0;                                // only thread 0's copy is used
    for (int base = 0; base < NN; base += 1024) {
        int i = base + tid;
        int x = (i < NN) ? cnt[i] : 0;
        int vx = x;                               // inclusive scan within wave
        #pragma unroll
        for (int o = 1; o < 64; o <<= 1) {
            int y = __shfl_up(vx, o, 64);
            if (lane >= o) vx += y;
        }
        if (lane == 63) wsums[wv] = vx;
        __syncthreads();
        if (tid == 0) {
            int s = carry;
            #pragma unroll
            for (int k = 0; k < 16; ++k) { int t2 = wsums[k]; wsums[k] = s; s += t2; }
            carry = s;
        }
        __syncthreads();
        if (i < NN) off[i] = wsums[wv] + (vx - x);
        __syncthreads();                          // protect wsums for next iter
    }
}

// ---------------------------------------------------------------------------
// Kernel 4: scatter triples into center-sorted slots. off[c] -> inclusive prefix.
// ---------------------------------------------------------------------------
__global__ __launch_bounds__(256) void scatter_kernel(
        const void* __restrict__ idxp,
        const void* __restrict__ d1p, const void* __restrict__ d2p,
        const int* __restrict__ flags, int* __restrict__ off,
        int* __restrict__ sn1, int* __restrict__ sn2, float* __restrict__ sw) {
    int t = blockIdx.x * 256 + threadIdx.x;
    if (t >= NT) return;
    int fb = flags[0];
    int c, n1, n2;
    if (flags[1]) {
        const long long* q = (const long long*)idxp;
        c = (int)q[3LL * t]; n1 = (int)q[3LL * t + 1]; n2 = (int)q[3LL * t + 2];
    } else {
        const int* q = (const int*)idxp;
        c = q[3 * t]; n1 = q[3 * t + 1]; n2 = q[3 * t + 2];
    }
    float d1 = ldf(d1p, t, fb);
    float d2 = ldf(d2p, t, fb);
    float w = 1.0f + 0.3f * (fabsf(d1 - d2) / (fmaxf(d1, d2) + 1e-8f));
    int pos = atomicAdd(&off[c], 1);
    sn1[pos] = n1;
    sn2[pos] = n2;
    sw[pos]  = w;
}

// ---------------------------------------------------------------------------
// Kernel 5: one wave per center. u[c] on the fly (LDS Wu1 + shfl-broadcast h[c]),
// register accumulation over the center's triple list, fused residual+LayerNorm.
// ---------------------------------------------------------------------------
__global__ __launch_bounds__(256) void accum_kernel(
        const void* __restrict__ h, const int* __restrict__ flags,
        const float* __restrict__ wu1f, const float* __restrict__ v,
        const int* __restrict__ cnt, const int* __restrict__ off,
        const int* __restrict__ sn1, const int* __restrict__ sn2,
        const float* __restrict__ sw,
        const void* __restrict__ gamma, const void* __restrict__ beta,
        void* __restrict__ out) {
    __shared__ float Wu1s[HD * 49];
    int tid = threadIdx.x;
    int fb = flags[0];
    for (int i = tid; i < HD * HD; i += 256)
        Wu1s[(i / HD) * 49 + (i % HD)] = wu1f[i];
    __syncthreads();

    int wv = tid >> 6, lane = tid & 63;
    int n = blockIdx.x * 4 + wv;                  // NN % 4 == 0
    int row = (lane < HD) ? lane : 0;

    float hval = 0.f;
    if (lane < HD) hval = ldf(h, (long long)n * HD + lane, fb);

    // u_c[lane] = sum_k Wu1[lane][k] * h[c][k]  via shuffle broadcast
    float uc = 0.f;
    const float* wr = Wu1s + row * 49;
    #pragma unroll
    for (int k = 0; k < HD; ++k)
        uc += wr[k] * __shfl(hval, k, 64);

    int start = (n == 0) ? 0 : off[n - 1];
    int end = off[n];
    float acc = 0.f;
    for (int p = start; p < end; ++p) {
        int n1 = sn1[p];                          // broadcast loads (same line)
        int n2 = sn2[p];
        float w = sw[p];
        float pre = uc + v[(size_t)n1 * HD + row] + v[(size_t)n2 * HD + row];
        acc += (pre > 0.f ? pre : 0.01f * pre) * w;
    }

    float rnc = rsqrtf(fmaxf((float)cnt[n], 1.0f));
    float x = (lane < HD) ? (hval + acc * rnc) : 0.f;
    float s = x, sq = x * x;
    #pragma unroll
    for (int o = 32; o; o >>= 1) {
        s  += __shfl_xor(s, o, 64);
        sq += __shfl_xor(sq, o, 64);
    }
    float mu   = s * (1.0f / HD);
    float var  = sq * (1.0f / HD) - mu * mu;
    float rstd = rsqrtf(var + 1e-5f);
    if (lane < HD) {
        float g  = ldf(gamma, lane, fb);
        float bb = ldf(beta, lane, fb);
        float r = (x - mu) * rstd * g + bb;
        if (fb) ((__hip_bfloat16*)out)[(size_t)n * HD + lane] = __float2bfloat16(r);
        else    ((float*)out)[(size_t)n * HD + lane] = r;
    }
}

extern "C" void kernel_launch(void* const* d_in, const int* in_sizes, int n_in,
                              void* d_out, int out_size, void* d_ws, size_t ws_size,
                              hipStream_t stream) {
    const void* h     = d_in[0];
    const void* idx   = d_in[1];
    const void* d1    = d_in[2];
    const void* d2    = d_in[3];
    const void* W3    = d_in[4];
    const void* Wu    = d_in[5];
    const void* gamma = d_in[6];
    const void* beta  = d_in[7];

    float* ws   = (float*)d_ws;
    int*   flags = (int*)ws;                        // 16 words
    float* wu1f = ws + 16;                          // 2304
    float* bf   = wu1f + HD * HD;                   // 2304
    float* v    = bf + HD * HD;                     // NN*48  (19.2 MB)
    int*   cnt  = (int*)(v + (size_t)NN * HD);      // NN
    int*   off  = cnt + NN;                         // NN
    int*   sn1  = off + NN;                         // NT (8 MB)
    int*   sn2  = sn1 + NT;                         // NT (8 MB)
    float* sw   = (float*)(sn2 + NT);               // NT (8 MB)  total ~44 MB

    hipMemsetAsync(cnt, 0, NN * sizeof(int), stream);

    probe_kernel<<<1, 256, 0, stream>>>((const unsigned int*)h,
                                        (const unsigned int*)idx, flags);
    prep_kernel<<<(HD * HD + 255) / 256, 256, 0, stream>>>(W3, Wu, flags, wu1f, bf);
    node_kernel<<<NN / 4, 192, 0, stream>>>(h, flags, bf, v);
    hist_kernel<<<(NT + 255) / 256, 256, 0, stream>>>(idx, flags, cnt);
    scan_kernel<<<1, 1024, 0, stream>>>(cnt, off);
    scatter_kernel<<<(NT + 255) / 256, 256, 0, stream>>>(idx, d1, d2, flags, off,
                                                         sn1, sn2, sw);
    accum_kernel<<<NN / 4, 256, 0, stream>>>(h, flags, wu1f, v, cnt, off,
                                             sn1, sn2, sw, gamma, beta, d_out);
}

// Round 4
// 586.471 us; speedup vs baseline: 8.8985x; 1.5002x over previous
//
#include <hip/hip_runtime.h>
#include <hip/hip_bf16.h>
#include <hip/hip_fp16.h>
#include <stdint.h>

#define NN 100000
#define NT 2000000
#define HD 48
#define NB ((NN + 1023) / 1024)   // 98 scan blocks

__device__ __forceinline__ float b2f(__hip_bfloat16 x) { return __bfloat162float(x); }

// Load a "float tensor" element whose storage is bf16 (flag=1) or f32 (flag=0).
__device__ __forceinline__ float ldf(const void* p, long long i, int isbf16) {
    if (isbf16) return b2f(((const __hip_bfloat16*)p)[i]);
    return ((const float*)p)[i];
}

// ---------------------------------------------------------------------------
// Kernel P: probe dtypes from raw bits.
// flags[0] = float tensors stored as bf16?   flags[1] = indices stored as int64?
// ---------------------------------------------------------------------------
__global__ void probe_kernel(const unsigned int* __restrict__ hw,
                             const unsigned int* __restrict__ iw,
                             int* __restrict__ flags) {
    __shared__ int cnt_bf, cnt_idx;
    if (threadIdx.x == 0) { cnt_bf = 0; cnt_idx = 0; }
    __syncthreads();
    unsigned int w = hw[threadIdx.x];
    unsigned int e = (w >> 7) & 0xff;            // exponent field of low-half bf16
    if (e >= 90 && e <= 144) atomicAdd(&cnt_bf, 1);
    if (iw[2 * threadIdx.x + 1] == 0) atomicAdd(&cnt_idx, 1);
    __syncthreads();
    if (threadIdx.x == 0) {
        flags[0] = (cnt_bf >= 192) ? 1 : 0;      // bf16 ~256 hits; f32 mantissa ~55
        flags[1] = (cnt_idx >= 255) ? 1 : 0;     // int64 high words all zero
    }
}

// ---------------------------------------------------------------------------
// Kernel 0: fold weights. wu1f[o][h] = Wu[o][h]; bf[o][h] = sum_k Wu[o][48+k]*W3[k][h]
// ---------------------------------------------------------------------------
__global__ void prep_kernel(const void* __restrict__ W3,
                            const void* __restrict__ Wu,
                            const int* __restrict__ flags,
                            float* __restrict__ wu1f, float* __restrict__ bf) {
    int i = blockIdx.x * blockDim.x + threadIdx.x;
    if (i >= HD * HD) return;
    int fb = flags[0];
    int o = i / HD, hh = i % HD;
    wu1f[i] = ldf(Wu, o * 2 * HD + hh, fb);
    float s = 0.f;
    #pragma unroll 8
    for (int k = 0; k < HD; ++k)
        s += ldf(Wu, o * 2 * HD + HD + k, fb) * ldf(W3, k * HD + hh, fb);
    bf[i] = s;
}

// ---------------------------------------------------------------------------
// Kernel 1: per-node v[n] = M*h[n], stored fp16 (halves gather traffic later).
// ---------------------------------------------------------------------------
__global__ __launch_bounds__(192) void node_kernel(
        const void* __restrict__ h, const int* __restrict__ flags,
        const float* __restrict__ bf, __half* __restrict__ vh) {
    __shared__ float Bs[HD * 49];
    __shared__ float hs[192];
    int tid = threadIdx.x;
    int fb = flags[0];
    for (int i = tid; i < HD * HD; i += 192)
        Bs[(i / HD) * 49 + (i % HD)] = bf[i];
    int base = blockIdx.x * 4;                    // NN % 4 == 0
    hs[tid] = ldf(h, (long long)base * HD + tid, fb);
    __syncthreads();

    int o  = tid % HD;
    int ln = tid / HD;
    const float* hrow = hs + ln * HD;
    const float* br = Bs + o * 49;
    float sv = 0.f;
    #pragma unroll
    for (int k = 0; k < HD; ++k) sv += br[k] * hrow[k];
    vh[(size_t)(base + ln) * HD + o] = __float2half(sv);
}

// ---------------------------------------------------------------------------
// Kernel 2: histogram of centers.
// ---------------------------------------------------------------------------
__global__ __launch_bounds__(256) void hist_kernel(const void* __restrict__ idxp,
                                                   const int* __restrict__ flags,
                                                   int* __restrict__ cnt) {
    int t = blockIdx.x * 256 + threadIdx.x;
    if (t >= NT) return;
    int c = flags[1] ? (int)((const long long*)idxp)[3LL * t]
                     : ((const int*)idxp)[3 * t];
    atomicAdd(&cnt[c], 1);
}

// ---------------------------------------------------------------------------
// Kernels 3a/3b/3c: parallel exclusive scan of cnt[NN] -> off[NN].
// ---------------------------------------------------------------------------
__global__ __launch_bounds__(1024) void scan_part(const int* __restrict__ cnt,
                                                  int* __restrict__ off,
                                                  int* __restrict__ bsum) {
    __shared__ int wsums[16];
    int tid = threadIdx.x, lane = tid & 63, wv = tid >> 6;
    int i = blockIdx.x * 1024 + tid;
    int x = (i < NN) ? cnt[i] : 0;
    int vx = x;
    #pragma unroll
    for (int o = 1; o < 64; o <<= 1) {
        int y = __shfl_up(vx, o, 64);
        if (lane >= o) vx += y;
    }
    if (lane == 63) wsums[wv] = vx;
    __syncthreads();
    if (tid == 0) {
        int s = 0;
        #pragma unroll
        for (int k = 0; k < 16; ++k) { int t2 = wsums[k]; wsums[k] = s; s += t2; }
        bsum[blockIdx.x] = s;
    }
    __syncthreads();
    if (i < NN) off[i] = wsums[wv] + vx - x;
}

__global__ void scan_tops(int* __restrict__ bsum) {
    __shared__ int sh[NB];
    int tid = threadIdx.x;
    if (tid < NB) sh[tid] = bsum[tid];
    __syncthreads();
    if (tid == 0) {
        int s = 0;
        for (int k = 0; k < NB; ++k) { int t = sh[k]; sh[k] = s; s += t; }
    }
    __syncthreads();
    if (tid < NB) bsum[tid] = sh[tid];
}

__global__ __launch_bounds__(1024) void scan_add(int* __restrict__ off,
                                                 const int* __restrict__ bsum) {
    int i = blockIdx.x * 1024 + threadIdx.x;
    if (i < NN) off[i] += bsum[blockIdx.x];
}

// ---------------------------------------------------------------------------
// Kernel 4: scatter triples into center-sorted slots as one aligned float4
// (n1, n2, w, pad). off[c] becomes the inclusive segment end.
// ---------------------------------------------------------------------------
__global__ __launch_bounds__(256) void scatter_kernel(
        const void* __restrict__ idxp,
        const void* __restrict__ d1p, const void* __restrict__ d2p,
        const int* __restrict__ flags, int* __restrict__ off,
        float4* __restrict__ sp) {
    int t = blockIdx.x * 256 + threadIdx.x;
    if (t >= NT) return;
    int fb = flags[0];
    int c, n1, n2;
    if (flags[1]) {
        const long long* q = (const long long*)idxp;
        c = (int)q[3LL * t]; n1 = (int)q[3LL * t + 1]; n2 = (int)q[3LL * t + 2];
    } else {
        const int* q = (const int*)idxp;
        c = q[3 * t]; n1 = q[3 * t + 1]; n2 = q[3 * t + 2];
    }
    float d1 = ldf(d1p, t, fb);
    float d2 = ldf(d2p, t, fb);
    float w = 1.0f + 0.3f * (fabsf(d1 - d2) / (fmaxf(d1, d2) + 1e-8f));
    int pos = atomicAdd(&off[c], 1);
    sp[pos] = make_float4(__int_as_float(n1), __int_as_float(n2), w, 0.f);
}

// ---------------------------------------------------------------------------
// Kernel 5: one wave per center. Meta for up to 64 triples batch-loaded
// coalesced into lanes, shfl-broadcast; inner loop unrolled x4 so 8 fp16-row
// gathers are in flight. Fused residual + LayerNorm epilogue.
// ---------------------------------------------------------------------------
__global__ __launch_bounds__(256) void accum_kernel(
        const void* __restrict__ h, const int* __restrict__ flags,
        const float* __restrict__ wu1f, const __half* __restrict__ vh,
        const int* __restrict__ off, const float4* __restrict__ sp,
        const void* __restrict__ gamma, const void* __restrict__ beta,
        void* __restrict__ out) {
    __shared__ float Wu1s[HD * 49];
    int tid = threadIdx.x;
    int fb = flags[0];
    for (int i = tid; i < HD * HD; i += 256)
        Wu1s[(i / HD) * 49 + (i % HD)] = wu1f[i];
    __syncthreads();

    int wv = tid >> 6, lane = tid & 63;
    int n = blockIdx.x * 4 + wv;                  // NN % 4 == 0
    int row = (lane < HD) ? lane : 0;

    float hval = (lane < HD) ? ldf(h, (long long)n * HD + lane, fb) : 0.f;

    // u_c[lane] = sum_k Wu1[lane][k] * h[c][k] via shuffle broadcast
    float uc = 0.f;
    const float* wr = Wu1s + row * 49;
    #pragma unroll
    for (int k = 0; k < HD; ++k)
        uc += wr[k] * __shfl(hval, k, 64);

    int start = (n == 0) ? 0 : off[n - 1];
    int end = off[n];
    float acc = 0.f;
    const __half* vrow = vh + row;

    for (int chunk = start; chunk < end; chunk += 64) {
        int m = end - chunk; if (m > 64) m = 64;
        float4 meta = make_float4(0.f, 0.f, 0.f, 0.f);
        if (lane < m) meta = sp[chunk + lane];
        int t = 0;
        for (; t + 4 <= m; t += 4) {
            int a0 = __float_as_int(__shfl(meta.x, t + 0, 64));
            int b0 = __float_as_int(__shfl(meta.y, t + 0, 64));
            float w0 = __shfl(meta.z, t + 0, 64);
            int a1 = __float_as_int(__shfl(meta.x, t + 1, 64));
            int b1 = __float_as_int(__shfl(meta.y, t + 1, 64));
            float w1 = __shfl(meta.z, t + 1, 64);
            int a2 = __float_as_int(__shfl(meta.x, t + 2, 64));
            int b2 = __float_as_int(__shfl(meta.y, t + 2, 64));
            float w2 = __shfl(meta.z, t + 2, 64);
            int a3 = __float_as_int(__shfl(meta.x, t + 3, 64));
            int b3 = __float_as_int(__shfl(meta.y, t + 3, 64));
            float w3 = __shfl(meta.z, t + 3, 64);
            __half va0 = vrow[a0 * HD];
            __half vb0 = vrow[b0 * HD];
            __half va1 = vrow[a1 * HD];
            __half vb1 = vrow[b1 * HD];
            __half va2 = vrow[a2 * HD];
            __half vb2 = vrow[b2 * HD];
            __half va3 = vrow[a3 * HD];
            __half vb3 = vrow[b3 * HD];
            float p0 = uc + __half2float(va0) + __half2float(vb0);
            float p1 = uc + __half2float(va1) + __half2float(vb1);
            float p2 = uc + __half2float(va2) + __half2float(vb2);
            float p3 = uc + __half2float(va3) + __half2float(vb3);
            acc += (p0 > 0.f ? p0 : 0.01f * p0) * w0;
            acc += (p1 > 0.f ? p1 : 0.01f * p1) * w1;
            acc += (p2 > 0.f ? p2 : 0.01f * p2) * w2;
            acc += (p3 > 0.f ? p3 : 0.01f * p3) * w3;
        }
        for (; t < m; ++t) {
            int a = __float_as_int(__shfl(meta.x, t, 64));
            int b = __float_as_int(__shfl(meta.y, t, 64));
            float w = __shfl(meta.z, t, 64);
            float pr = uc + __half2float(vrow[a * HD]) + __half2float(vrow[b * HD]);
            acc += (pr > 0.f ? pr : 0.01f * pr) * w;
        }
    }

    float rnc = rsqrtf(fmaxf((float)(end - start), 1.0f));
    float x = (lane < HD) ? (hval + acc * rnc) : 0.f;
    float s = x, sq = x * x;
    #pragma unroll
    for (int o = 32; o; o >>= 1) {
        s  += __shfl_xor(s, o, 64);
        sq += __shfl_xor(sq, o, 64);
    }
    float mu   = s * (1.0f / HD);
    float var  = sq * (1.0f / HD) - mu * mu;
    float rstd = rsqrtf(var + 1e-5f);
    if (lane < HD) {
        float g  = ldf(gamma, lane, fb);
        float bb = ldf(beta, lane, fb);
        float r = (x - mu) * rstd * g + bb;
        if (fb) ((__hip_bfloat16*)out)[(size_t)n * HD + lane] = __float2bfloat16(r);
        else    ((float*)out)[(size_t)n * HD + lane] = r;
    }
}

extern "C" void kernel_launch(void* const* d_in, const int* in_sizes, int n_in,
                              void* d_out, int out_size, void* d_ws, size_t ws_size,
                              hipStream_t stream) {
    const void* h     = d_in[0];
    const void* idx   = d_in[1];
    const void* d1    = d_in[2];
    const void* d2    = d_in[3];
    const void* W3    = d_in[4];
    const void* Wu    = d_in[5];
    const void* gamma = d_in[6];
    const void* beta  = d_in[7];

    char* base  = (char*)d_ws;
    int*   flags = (int*)base;                              // 64 B
    float* wu1f  = (float*)(base + 64);                     // 2304 f
    float* bf    = wu1f + HD * HD;                          // 2304 f
    __half* vh   = (__half*)(bf + HD * HD);                 // NN*48 fp16 (9.6 MB)
    int*   cnt   = (int*)(vh + (size_t)NN * HD);            // NN
    int*   off   = cnt + NN;                                // NN
    int*   bsum  = off + NN;                                // NB (+pad)
    uintptr_t spa = (uintptr_t)(bsum + 256);
    float4* sp   = (float4*)((spa + 15) & ~(uintptr_t)15);  // NT float4 (32 MB)

    hipMemsetAsync(cnt, 0, NN * sizeof(int), stream);

    probe_kernel<<<1, 256, 0, stream>>>((const unsigned int*)h,
                                        (const unsigned int*)idx, flags);
    prep_kernel<<<(HD * HD + 255) / 256, 256, 0, stream>>>(W3, Wu, flags, wu1f, bf);
    node_kernel<<<NN / 4, 192, 0, stream>>>(h, flags, bf, vh);
    hist_kernel<<<(NT + 255) / 256, 256, 0, stream>>>(idx, flags, cnt);
    scan_part<<<NB, 1024, 0, stream>>>(cnt, off, bsum);
    scan_tops<<<1, 128, 0, stream>>>(bsum);
    scan_add<<<NB, 1024, 0, stream>>>(off, bsum);
    scatter_kernel<<<(NT + 255) / 256, 256, 0, stream>>>(idx, d1, d2, flags, off, sp);
    accum_kernel<<<NN / 4, 256, 0, stream>>>(h, flags, wu1f, vh, off, sp,
                                             gamma, beta, d_out);
}